// Round 3
// baseline (66277.972 us; speedup 1.0000x reference)
//
#include <hip/hip_runtime.h>
#include <float.h>

// TransitionDown: FPS -> kNN(16) -> Linear(64,128)+BN(train stats)+ReLU -> neighborhood max
#define N_PTS 32768
#define M_CL  8192
#define IN_C  64
#define OUT_C 128
#define K_NN  16
constexpr float BN_EPS_C = 1e-5f;

// ---------------- ws layout (bytes) ----------------
// 0        posx [N] f32          (prep -> knn)
// 131072   posy [N]
// 262144   posz [N]
// 393216   psx  [N] sorted       (scatter -> fps)   [reused as psum after fps]
// 524288   psy  [N]
// 655360   psz  [N]              [reused as psumsq after fps]
// 786432   soidx[N] int
// 917504   cellid [N] int        (prep -> scatter)
// 1048576  hist [4096] int       [reused as scale/shift after scatter]
// 1064960  start [4096] int
// 1081344  cur  [4096] int
// 1097728  ids  [M] int          (fps -> knn)
// 1130496  nn   [M*16] int       (knn -> pool)
// 2097152  h [N*128] f32 (16 MiB) -> end 18874368

// ---------------------------------------------------------------------------
__global__ void zero_kernel(int* __restrict__ hist, int* __restrict__ cur) {
    int i = blockIdx.x * 256 + threadIdx.x;
    if (i < 4096) { hist[i] = 0; cur[i] = 0; }
}

// spread 4 bits to positions 0,3,6,9
__device__ __forceinline__ unsigned sp4(unsigned x) {
    x = (x | (x << 4)) & 0xC3u;
    x = (x | (x << 2)) & 0x249u;
    return x;
}

// 0) SoA split + Morton cell id + histogram
__global__ void prep_kernel(const float* __restrict__ pos,
                            float* __restrict__ px, float* __restrict__ py, float* __restrict__ pz,
                            int* __restrict__ cellid, int* __restrict__ hist) {
    int i = blockIdx.x * 256 + threadIdx.x;
    if (i >= N_PTS) return;
    float x = pos[3 * i + 0], y = pos[3 * i + 1], z = pos[3 * i + 2];
    px[i] = x; py[i] = y; pz[i] = z;
    int cx = (int)floorf((x + 4.0f) * 2.0f); cx = min(15, max(0, cx));
    int cy = (int)floorf((y + 4.0f) * 2.0f); cy = min(15, max(0, cy));
    int cz = (int)floorf((z + 4.0f) * 2.0f); cz = min(15, max(0, cz));
    int c = (int)(sp4((unsigned)cx) | (sp4((unsigned)cy) << 1) | (sp4((unsigned)cz) << 2));
    cellid[i] = c;
    atomicAdd(&hist[c], 1);
}

// exclusive prefix sum over 4096 bins; 1 block x 1024 threads, 4 bins/thread
__global__ __launch_bounds__(1024) void scan_kernel(const int* __restrict__ hist,
                                                    int* __restrict__ start) {
    __shared__ int wtotI[16];
    const int tid = threadIdx.x;
    const int lane = tid & 63, w = tid >> 6;
    int4 hv = *reinterpret_cast<const int4*>(&hist[tid * 4]);
    int a0 = hv.x, a1 = a0 + hv.y, a2 = a1 + hv.z, a3 = a2 + hv.w;
    int tsum = a3;
    int v = tsum;
    #pragma unroll
    for (int off = 1; off < 64; off <<= 1) {
        int o = __shfl_up(v, off);
        if (lane >= off) v += o;
    }
    if (lane == 63) wtotI[w] = v;
    __syncthreads();
    if (tid < 16) {
        int v2 = wtotI[tid];
        #pragma unroll
        for (int off = 1; off < 16; off <<= 1) {
            int o = __shfl_up(v2, off);
            if (tid >= off) v2 += o;
        }
        wtotI[tid] = v2;  // inclusive wave totals
    }
    __syncthreads();
    int base = (w > 0 ? wtotI[w - 1] : 0) + (v - tsum);
    int4 sv;
    sv.x = base; sv.y = base + a0; sv.z = base + a1; sv.w = base + a2;
    *reinterpret_cast<int4*>(&start[tid * 4]) = sv;
}

// counting-sort scatter (within-cell order nondeterministic; results invariant)
__global__ void scatter_kernel(const float* __restrict__ px, const float* __restrict__ py,
                               const float* __restrict__ pz, const int* __restrict__ cellid,
                               const int* __restrict__ start, int* __restrict__ cur,
                               float* __restrict__ psx, float* __restrict__ psy,
                               float* __restrict__ psz, int* __restrict__ soidx) {
    int i = blockIdx.x * 256 + threadIdx.x;
    if (i >= N_PTS) return;
    int c = cellid[i];
    int p = start[c] + atomicAdd(&cur[c], 1);
    psx[p] = px[i]; psy[p] = py[i]; psz[p] = pz[i];
    soidx[p] = i;
}

// ---------------------------------------------------------------------------
// 1) Pruned FPS. 512 threads; thread r owns sorted region [r*64, r*64+64).
//    min_d in LDS, rotation-swizzled: slot(r,j) = r*64 + ((j+r)&63)
//    (conflict-free for both per-lane flat and wave-coop access).
//    Distance arithmetic bit-identical to jax f32: unfused, (xx+yy)+zz.
//    All selections/ties identical to the flat R2 kernel (pruning only skips
//    provably value-preserving fminf updates; conservative f32 slop).
__global__ __launch_bounds__(512) void fps_kernel(
    const float* __restrict__ psx, const float* __restrict__ psy, const float* __restrict__ psz,
    const int* __restrict__ soidx, const float* __restrict__ pos, const int* __restrict__ batch,
    int* __restrict__ ids, float* __restrict__ out_subpos, float* __restrict__ out_subbatch) {
    #pragma clang fp contract(off)
    __shared__ __align__(16) float mdL[N_PTS];  // 128 KiB
    __shared__ float cm[512];
    __shared__ int   ci[512];
    __shared__ float rv[2][8];
    __shared__ int   ri[2][8];

    const int tid = threadIdx.x;
    const int lane = tid & 63, w = tid >> 6;
    const int r = tid, rb = r * 64;

    // ---- init: region load, bbox, min_d vs point 0, cached (cmax,cidx) ----
    float s0x = pos[0], s0y = pos[1], s0z = pos[2];
    float mnx = FLT_MAX, mxx = -FLT_MAX, mny = FLT_MAX, mxy = -FLT_MAX, mnz = FLT_MAX, mxz = -FLT_MAX;
    float cmax = -1.0f; int cidx = 0x7fffffff;
    #pragma unroll
    for (int k = 0; k < 16; ++k) {
        float4 xv = *reinterpret_cast<const float4*>(&psx[rb + 4 * k]);
        float4 yv = *reinterpret_cast<const float4*>(&psy[rb + 4 * k]);
        float4 zv = *reinterpret_cast<const float4*>(&psz[rb + 4 * k]);
        int4   ov = *reinterpret_cast<const int4*>(&soidx[rb + 4 * k]);
        #pragma unroll
        for (int e = 0; e < 4; ++e) {
            float X = (&xv.x)[e], Y = (&yv.x)[e], Z = (&zv.x)[e];
            int   o = (&ov.x)[e];
            mnx = fminf(mnx, X); mxx = fmaxf(mxx, X);
            mny = fminf(mny, Y); mxy = fmaxf(mxy, Y);
            mnz = fminf(mnz, Z); mxz = fmaxf(mxz, Z);
            float dx = X - s0x, dy = Y - s0y, dz = Z - s0z;
            float xx = dx * dx, yy = dy * dy, zz = dz * dz;
            float d = (xx + yy) + zz;
            int j = 4 * k + e;
            mdL[rb + ((j + r) & 63)] = d;
            if (d > cmax || (d == cmax && o < cidx)) { cmax = d; cidx = o; }
        }
    }
    const float cenx = 0.5f * (mnx + mxx), ceny = 0.5f * (mny + mxy), cenz = 0.5f * (mnz + mxz);
    float hx = mxx - cenx, hy = mxy - ceny, hz = mxz - cenz;
    const float rad = sqrtf((hx * hx + hy * hy) + hz * hz) * 1.0005f + 1e-6f;
    cm[r] = cmax; ci[r] = cidx;
    if (tid == 0) {
        ids[0] = 0;
        out_subpos[0] = s0x; out_subpos[1] = s0y; out_subpos[2] = s0z;
        out_subbatch[0] = (float)batch[0];
    }
    __syncthreads();

    // ---- main loop ----
    for (int t = 1; t < M_CL; ++t) {
        const int p2 = t & 1;
        float mycm = cm[r];
        int   myci = ci[r];
        // wave partial lex-max
        float v = mycm; int bi = myci;
        #pragma unroll
        for (int off = 32; off; off >>= 1) {
            float ov2 = __shfl_xor(v, off);
            int   oi2 = __shfl_xor(bi, off);
            if (ov2 > v || (ov2 == v && oi2 < bi)) { v = ov2; bi = oi2; }
        }
        if (lane == 0) { rv[p2][w] = v; ri[p2][w] = bi; }
        __syncthreads();
        // redundant final reduce (all threads)
        float bv = rv[p2][0]; int bb = ri[p2][0];
        #pragma unroll
        for (int u = 1; u < 8; ++u) {
            float ov2 = rv[p2][u]; int oi2 = ri[p2][u];
            if (ov2 > bv || (ov2 == bv && oi2 < bb)) { bv = ov2; bb = oi2; }
        }
        const int i2 = bb;
        const float sx = pos[3 * i2 + 0], sy = pos[3 * i2 + 1], sz = pos[3 * i2 + 2];
        if (tid == 0) {
            ids[t] = i2;
            out_subpos[3 * t + 0] = sx;
            out_subpos[3 * t + 1] = sy;
            out_subpos[3 * t + 2] = sz;
            out_subbatch[t] = (float)batch[i2];
        }
        // conservative region prune test
        float ex = sx - cenx, ey = sy - ceny, ez = sz - cenz;
        float dc2 = (ex * ex + ey * ey) + ez * ez;
        float lb = sqrtf(dc2) * 0.9995f - rad;
        bool aff = !(lb > 0.0f && lb * lb * 0.999f >= mycm);
        unsigned long long m = __ballot(aff);
        int cnt = __popcll(m);
        if (cnt > 12) {
            // flat: each affected lane updates its own region
            if (aff) {
                float ncm = -1.0f; int nci = 0x7fffffff;
                #pragma unroll
                for (int k = 0; k < 16; ++k) {
                    float4 xv = *reinterpret_cast<const float4*>(&psx[rb + 4 * k]);
                    float4 yv = *reinterpret_cast<const float4*>(&psy[rb + 4 * k]);
                    float4 zv = *reinterpret_cast<const float4*>(&psz[rb + 4 * k]);
                    int4   ov = *reinterpret_cast<const int4*>(&soidx[rb + 4 * k]);
                    #pragma unroll
                    for (int e = 0; e < 4; ++e) {
                        float X = (&xv.x)[e], Y = (&yv.x)[e], Z = (&zv.x)[e];
                        int   o = (&ov.x)[e];
                        int j = 4 * k + e;
                        int slot = rb + ((j + r) & 63);
                        float dx = X - sx, dy = Y - sy, dz = Z - sz;
                        float xx = dx * dx, yy = dy * dy, zz = dz * dz;
                        float d = (xx + yy) + zz;
                        float nm = fminf(mdL[slot], d);
                        mdL[slot] = nm;
                        if (nm > ncm || (nm == ncm && o < nci)) { ncm = nm; nci = o; }
                    }
                }
                cm[r] = ncm; ci[r] = nci;
            }
        } else {
            // coop: whole wave updates each affected region (1 point/lane)
            unsigned long long mm = m;
            while (mm) {
                int b = (int)__ffsll(mm) - 1; mm &= mm - 1;
                int rr = (w << 6) + b;
                int p = rr * 64 + lane;
                int slot = rr * 64 + ((lane + rr) & 63);
                float X = psx[p], Y = psy[p], Z = psz[p];
                int   o = soidx[p];
                float dx = X - sx, dy = Y - sy, dz = Z - sz;
                float xx = dx * dx, yy = dy * dy, zz = dz * dz;
                float d = (xx + yy) + zz;
                float nm = fminf(mdL[slot], d);
                mdL[slot] = nm;
                float vv = nm; int vb = o;
                #pragma unroll
                for (int off = 32; off; off >>= 1) {
                    float ov2 = __shfl_xor(vv, off);
                    int   oi2 = __shfl_xor(vb, off);
                    if (ov2 > vv || (ov2 == vv && oi2 < vb)) { vv = ov2; vb = oi2; }
                }
                if (lane == 0) { cm[rr] = vv; ci[rr] = vb; }
            }
        }
    }
}

// ---------------------------------------------------------------------------
// 2) GEMM h = x@W + b (f32 vector ALU) + fused per-block column sum / sumsq.
__global__ __launch_bounds__(256) void gemm_stats_kernel(
    const float* __restrict__ x, const float* __restrict__ W, const float* __restrict__ bias,
    float* __restrict__ h, float* __restrict__ psum, float* __restrict__ psumsq) {
    __shared__ __align__(16) float Wl[64 * 128];
    __shared__ float xl[64 * 64];
    __shared__ float st[8 * 128 * 2];

    const int t = threadIdx.x;
    const int r0 = blockIdx.x * 64;
    #pragma unroll
    for (int u = 0; u < 32; ++u) Wl[u * 256 + t] = W[u * 256 + t];
    #pragma unroll
    for (int u = 0; u < 16; ++u) { int f = u * 256 + t; xl[f] = x[r0 * 64 + f]; }
    __syncthreads();

    const int cg = t & 31;
    const int rg = t >> 5;
    float acc[8][4];
    #pragma unroll
    for (int j = 0; j < 8; ++j)
        #pragma unroll
        for (int cc = 0; cc < 4; ++cc) acc[j][cc] = 0.0f;

    #pragma unroll 4
    for (int k = 0; k < 64; ++k) {
        float4 w4 = *reinterpret_cast<const float4*>(&Wl[k * 128 + cg * 4]);
        #pragma unroll
        for (int j = 0; j < 8; ++j) {
            float xv = xl[(rg * 8 + j) * 64 + k];
            acc[j][0] = fmaf(xv, w4.x, acc[j][0]);
            acc[j][1] = fmaf(xv, w4.y, acc[j][1]);
            acc[j][2] = fmaf(xv, w4.z, acc[j][2]);
            acc[j][3] = fmaf(xv, w4.w, acc[j][3]);
        }
    }
    float4 b4 = *reinterpret_cast<const float4*>(&bias[cg * 4]);
    float s1[4] = {0, 0, 0, 0}, s2[4] = {0, 0, 0, 0};
    #pragma unroll
    for (int j = 0; j < 8; ++j) {
        float4 hv;
        hv.x = acc[j][0] + b4.x;
        hv.y = acc[j][1] + b4.y;
        hv.z = acc[j][2] + b4.z;
        hv.w = acc[j][3] + b4.w;
        *reinterpret_cast<float4*>(&h[(r0 + rg * 8 + j) * 128 + cg * 4]) = hv;
        s1[0] += hv.x; s2[0] += hv.x * hv.x;
        s1[1] += hv.y; s2[1] += hv.y * hv.y;
        s1[2] += hv.z; s2[2] += hv.z * hv.z;
        s1[3] += hv.w; s2[3] += hv.w * hv.w;
    }
    #pragma unroll
    for (int cc = 0; cc < 4; ++cc) {
        st[(rg * 128 + cg * 4 + cc) * 2 + 0] = s1[cc];
        st[(rg * 128 + cg * 4 + cc) * 2 + 1] = s2[cc];
    }
    __syncthreads();
    if (t < 128) {
        float a = 0.0f, q = 0.0f;
        #pragma unroll
        for (int g = 0; g < 8; ++g) {
            a += st[(g * 128 + t) * 2 + 0];
            q += st[(g * 128 + t) * 2 + 1];
        }
        psum[blockIdx.x * 128 + t] = a;
        psumsq[blockIdx.x * 128 + t] = q;
    }
}

// ---------------------------------------------------------------------------
__global__ void bn_finalize_kernel(const float* __restrict__ psum, const float* __restrict__ psumsq,
                                   const float* __restrict__ gamma, const float* __restrict__ beta,
                                   float* __restrict__ scale, float* __restrict__ shift) {
    int c = threadIdx.x;
    float s = 0.0f, q = 0.0f;
    #pragma unroll 8
    for (int p = 0; p < 512; ++p) {
        s += psum[p * 128 + c];
        q += psumsq[p * 128 + c];
    }
    float mean = s * (1.0f / N_PTS);
    float var = q * (1.0f / N_PTS) - mean * mean;
    float sc = gamma[c] * rsqrtf(var + BN_EPS_C);
    scale[c] = sc;
    shift[c] = beta[c] - mean * sc;
}

// ---------------------------------------------------------------------------
// 4) kNN: one wave per query; per-lane top-16 lex (d, idx); shuffle merge.
__global__ __launch_bounds__(256) void knn_kernel(
    const float* __restrict__ posx, const float* __restrict__ posy, const float* __restrict__ posz,
    const int* __restrict__ ids, int* __restrict__ nn) {
    const int lane = threadIdx.x & 63;
    const int q = blockIdx.x * 4 + (threadIdx.x >> 6);
    const int qi = ids[q];
    const float qx = posx[qi], qy = posy[qi], qz = posz[qi];

    float dv[16]; int di[16];
    #pragma unroll
    for (int j = 0; j < 16; ++j) { dv[j] = FLT_MAX; di[j] = 0x7fffffff; }
    float wm = FLT_MAX; int wmi = 0x7fffffff; int wslot = 0;

    for (int s = 0; s < N_PTS / 64; ++s) {
        int i = s * 64 + lane;
        float dx = posx[i] - qx, dy = posy[i] - qy, dz = posz[i] - qz;
        float d = fmaf(dx, dx, fmaf(dy, dy, dz * dz));
        if (d < wm || (d == wm && i < wmi)) {
            #pragma unroll
            for (int j = 0; j < 16; ++j)
                if (j == wslot) { dv[j] = d; di[j] = i; }
            wm = -1.0f; wmi = -1;
            #pragma unroll
            for (int j = 0; j < 16; ++j) {
                bool g = (dv[j] > wm) || (dv[j] == wm && di[j] > wmi);
                if (g) { wm = dv[j]; wmi = di[j]; wslot = j; }
            }
        }
    }
    for (int rr = 0; rr < 16; ++rr) {
        float bv = FLT_MAX; int bidx = 0x7fffffff;
        #pragma unroll
        for (int j = 0; j < 16; ++j) {
            bool g = (dv[j] < bv) || (dv[j] == bv && di[j] < bidx);
            if (g) { bv = dv[j]; bidx = di[j]; }
        }
        #pragma unroll
        for (int off = 32; off; off >>= 1) {
            float ov = __shfl_xor(bv, off);
            int oi = __shfl_xor(bidx, off);
            if (ov < bv || (ov == bv && oi < bidx)) { bv = ov; bidx = oi; }
        }
        if (lane == 0) nn[q * 16 + rr] = bidx;
        #pragma unroll
        for (int j = 0; j < 16; ++j)
            if (di[j] == bidx) { dv[j] = FLT_MAX; di[j] = 0x7fffffff; }
    }
}

// ---------------------------------------------------------------------------
__global__ __launch_bounds__(256) void pool_kernel(
    const float* __restrict__ h, const int* __restrict__ nn,
    const float* __restrict__ scale, const float* __restrict__ shift,
    float* __restrict__ out) {
    const int t = threadIdx.x;
    const int c = t & 127;
    const int m = blockIdx.x * 2 + (t >> 7);
    const float sc = scale[c], sh = shift[c];
    float mx = -FLT_MAX;
    #pragma unroll
    for (int k = 0; k < 16; ++k) {
        int n = nn[m * 16 + k];
        float hv = h[n * 128 + c];
        mx = fmaxf(mx, fmaf(hv, sc, sh));
    }
    out[m * 128 + c] = fmaxf(mx, 0.0f);
}

// ---------------------------------------------------------------------------
extern "C" void kernel_launch(void* const* d_in, const int* in_sizes, int n_in,
                              void* d_out, int out_size, void* d_ws, size_t ws_size,
                              hipStream_t stream) {
    const float* x     = (const float*)d_in[0];
    const float* pos   = (const float*)d_in[1];
    const int*   batch = (const int*)d_in[2];
    const float* W     = (const float*)d_in[3];
    const float* b     = (const float*)d_in[4];
    const float* gamma = (const float*)d_in[5];
    const float* beta  = (const float*)d_in[6];
    (void)in_sizes; (void)n_in; (void)out_size; (void)ws_size;

    float* out       = (float*)d_out;
    float* sub_pos   = out + (size_t)M_CL * OUT_C;
    float* sub_batch = sub_pos + (size_t)M_CL * 3;

    char* w8 = (char*)d_ws;
    float* posx   = (float*)(w8 + 0);
    float* posy   = (float*)(w8 + 131072);
    float* posz   = (float*)(w8 + 262144);
    float* psx    = (float*)(w8 + 393216);
    float* psy    = (float*)(w8 + 524288);
    float* psz    = (float*)(w8 + 655360);
    int*   soidx  = (int*)  (w8 + 786432);
    int*   cellid = (int*)  (w8 + 917504);
    int*   hist   = (int*)  (w8 + 1048576);
    int*   startb = (int*)  (w8 + 1064960);
    int*   cur    = (int*)  (w8 + 1081344);
    int*   ids    = (int*)  (w8 + 1097728);
    int*   nn     = (int*)  (w8 + 1130496);
    // dead-region reuse (stream-ordered):
    float* psum   = (float*)(w8 + 393216);   // over psx/psy (dead after fps)
    float* psumsq = (float*)(w8 + 655360);   // over psz/soidx (dead after fps)
    float* scale  = (float*)(w8 + 1048576);  // over hist (dead after scatter)
    float* shift  = (float*)(w8 + 1049088);
    float* h      = (float*)(w8 + 2097152);

    zero_kernel<<<32, 256, 0, stream>>>(hist, cur);
    prep_kernel<<<128, 256, 0, stream>>>(pos, posx, posy, posz, cellid, hist);
    scan_kernel<<<1, 1024, 0, stream>>>(hist, startb);
    scatter_kernel<<<128, 256, 0, stream>>>(posx, posy, posz, cellid, startb, cur,
                                            psx, psy, psz, soidx);
    fps_kernel<<<1, 512, 0, stream>>>(psx, psy, psz, soidx, pos, batch,
                                      ids, sub_pos, sub_batch);
    gemm_stats_kernel<<<512, 256, 0, stream>>>(x, W, b, h, psum, psumsq);
    bn_finalize_kernel<<<1, 128, 0, stream>>>(psum, psumsq, gamma, beta, scale, shift);
    knn_kernel<<<2048, 256, 0, stream>>>(posx, posy, posz, ids, nn);
    pool_kernel<<<4096, 256, 0, stream>>>(h, nn, scale, shift, out);
}

// Round 4
// 52658.337 us; speedup vs baseline: 1.2586x; 1.2586x over previous
//
#include <hip/hip_runtime.h>
#include <float.h>

// TransitionDown: FPS -> kNN(16) -> Linear(64,128)+BN(train stats)+ReLU -> neighborhood max
#define N_PTS 32768
#define M_CL  8192
#define IN_C  64
#define OUT_C 128
#define K_NN  16
constexpr float BN_EPS_C = 1e-5f;

// ---------------- ws layout (bytes) ----------------
// 0        posx [N] f32          (prep -> fps/knn)
// 131072   posy [N]
// 262144   posz [N]
// 393216   psx  [N] sorted       (scatter -> fps)   [psum after fps]
// 524288   psy  [N]
// 655360   psz  [N]              [psumsq after fps]
// 786432   soidx[N] int
// 917504   cellid [N] int        (prep -> scatter)
// 1048576  hist [4096] int       [scale/shift after scatter]
// 1064960  start [4096] int
// 1081344  cur  [4096] int
// 1097728  ids  [M] int          (fps -> knn)
// 1130496  nn   [M*16] int       (knn -> pool)
// 2097152  h [N*128] f32 (16 MiB) -> end 18874368

// ---------------------------------------------------------------------------
__global__ void zero_kernel(int* __restrict__ hist, int* __restrict__ cur) {
    int i = blockIdx.x * 256 + threadIdx.x;
    if (i < 4096) { hist[i] = 0; cur[i] = 0; }
}

__device__ __forceinline__ unsigned sp4(unsigned x) {
    x = (x | (x << 4)) & 0xC3u;
    x = (x | (x << 2)) & 0x249u;
    return x;
}

// 0) SoA split + Morton cell id + histogram
__global__ void prep_kernel(const float* __restrict__ pos,
                            float* __restrict__ px, float* __restrict__ py, float* __restrict__ pz,
                            int* __restrict__ cellid, int* __restrict__ hist) {
    int i = blockIdx.x * 256 + threadIdx.x;
    if (i >= N_PTS) return;
    float x = pos[3 * i + 0], y = pos[3 * i + 1], z = pos[3 * i + 2];
    px[i] = x; py[i] = y; pz[i] = z;
    int cx = (int)floorf((x + 4.0f) * 2.0f); cx = min(15, max(0, cx));
    int cy = (int)floorf((y + 4.0f) * 2.0f); cy = min(15, max(0, cy));
    int cz = (int)floorf((z + 4.0f) * 2.0f); cz = min(15, max(0, cz));
    int c = (int)(sp4((unsigned)cx) | (sp4((unsigned)cy) << 1) | (sp4((unsigned)cz) << 2));
    cellid[i] = c;
    atomicAdd(&hist[c], 1);
}

// exclusive prefix sum over 4096 bins
__global__ __launch_bounds__(1024) void scan_kernel(const int* __restrict__ hist,
                                                    int* __restrict__ start) {
    __shared__ int wtotI[16];
    const int tid = threadIdx.x;
    const int lane = tid & 63, w = tid >> 6;
    int4 hv = *reinterpret_cast<const int4*>(&hist[tid * 4]);
    int a0 = hv.x, a1 = a0 + hv.y, a2 = a1 + hv.z, a3 = a2 + hv.w;
    int tsum = a3;
    int v = tsum;
    #pragma unroll
    for (int off = 1; off < 64; off <<= 1) {
        int o = __shfl_up(v, off);
        if (lane >= off) v += o;
    }
    if (lane == 63) wtotI[w] = v;
    __syncthreads();
    if (tid < 16) {
        int v2 = wtotI[tid];
        #pragma unroll
        for (int off = 1; off < 16; off <<= 1) {
            int o = __shfl_up(v2, off);
            if (tid >= off) v2 += o;
        }
        wtotI[tid] = v2;
    }
    __syncthreads();
    int base = (w > 0 ? wtotI[w - 1] : 0) + (v - tsum);
    int4 sv;
    sv.x = base; sv.y = base + a0; sv.z = base + a1; sv.w = base + a2;
    *reinterpret_cast<int4*>(&start[tid * 4]) = sv;
}

__global__ void scatter_kernel(const float* __restrict__ px, const float* __restrict__ py,
                               const float* __restrict__ pz, const int* __restrict__ cellid,
                               const int* __restrict__ start, int* __restrict__ cur,
                               float* __restrict__ psx, float* __restrict__ psy,
                               float* __restrict__ psz, int* __restrict__ soidx) {
    int i = blockIdx.x * 256 + threadIdx.x;
    if (i >= N_PTS) return;
    int c = cellid[i];
    int p = start[c] + atomicAdd(&cur[c], 1);
    psx[p] = px[i]; psy[p] = py[i]; psz[p] = pz[i];
    soidx[p] = i;
}

// ---------------------------------------------------------------------------
// 1) FPS, lane-distributed registers.
//    512 thr / 8 waves. Wave w owns sorted points [w*4096,(w+1)*4096) as
//    32 regions x 128; lane l holds 2 coords+origidx per region in REGISTERS
//    (all indexing compile-time). min_d in LDS. Region meta on lane k.
//    Keys: u64 = (f32bits(min_d) << 32) | (0x7fffffff - origidx)  -> single
//    u64 max == lex (value desc, idx asc) == np.argmax first-occurrence.
//    Distance arithmetic bit-identical to jax f32: unfused, (xx+yy)+zz.
__global__ __launch_bounds__(512, 2) void fps_kernel(
    const float* __restrict__ psx, const float* __restrict__ psy, const float* __restrict__ psz,
    const int* __restrict__ soidx,
    const float* __restrict__ posx, const float* __restrict__ posy, const float* __restrict__ posz,
    const int* __restrict__ batch,
    int* __restrict__ ids, float* __restrict__ out_subpos, float* __restrict__ out_subbatch) {
    #pragma clang fp contract(off)
    __shared__ __align__(16) float mdL[N_PTS];          // 128 KiB
    __shared__ unsigned long long rv64[2][8];

    const int tid = threadIdx.x;
    const int lane = tid & 63, w = tid >> 6;
    const int wb = w * 4096;

    float cxr[32][2], cyr[32][2], czr[32][2];
    unsigned oidr[32][2];
    float cenx = 0.0f, ceny = 0.0f, cenz = 0.0f, rad = 0.0f, cmaxf = 0.0f;
    unsigned long long ckey = 0ull, wavemax = 0ull;

    const float s0x = posx[0], s0y = posy[0], s0z = posz[0];

    // ---- init: load region points, md vs point 0, bbox + cache per region ----
    #pragma unroll
    for (int k = 0; k < 32; ++k) {
        unsigned long long rk = 0ull;
        float mnx = FLT_MAX, mxx = -FLT_MAX;
        float mny = FLT_MAX, mxy = -FLT_MAX;
        float mnz = FLT_MAX, mxz = -FLT_MAX;
        #pragma unroll
        for (int p = 0; p < 2; ++p) {
            int gi = wb + k * 128 + p * 64 + lane;
            float X = psx[gi], Y = psy[gi], Z = psz[gi];
            unsigned o = (unsigned)soidx[gi];
            cxr[k][p] = X; cyr[k][p] = Y; czr[k][p] = Z; oidr[k][p] = o;
            mnx = fminf(mnx, X); mxx = fmaxf(mxx, X);
            mny = fminf(mny, Y); mxy = fmaxf(mxy, Y);
            mnz = fminf(mnz, Z); mxz = fmaxf(mxz, Z);
            float dx = X - s0x;
            float dy = Y - s0y;
            float dz = Z - s0z;
            float xx = dx * dx, yy = dy * dy, zz = dz * dz;
            float d = (xx + yy) + zz;
            mdL[gi] = d;
            unsigned long long kp = ((unsigned long long)__float_as_uint(d) << 32)
                                  | (unsigned long long)(0x7fffffffu - o);
            if (kp > rk) rk = kp;
        }
        #pragma unroll
        for (int off = 32; off; off >>= 1) {
            unsigned long long ok = __shfl_xor(rk, off);
            if (ok > rk) rk = ok;
            mnx = fminf(mnx, __shfl_xor(mnx, off)); mxx = fmaxf(mxx, __shfl_xor(mxx, off));
            mny = fminf(mny, __shfl_xor(mny, off)); mxy = fmaxf(mxy, __shfl_xor(mxy, off));
            mnz = fminf(mnz, __shfl_xor(mnz, off)); mxz = fmaxf(mxz, __shfl_xor(mxz, off));
        }
        if (lane == k) {
            cenx = 0.5f * (mnx + mxx); ceny = 0.5f * (mny + mxy); cenz = 0.5f * (mnz + mxz);
            float hx = mxx - cenx, hy = mxy - ceny, hz = mxz - cenz;
            rad = sqrtf((hx * hx + hy * hy) + hz * hz) * 1.0005f + 1e-6f;
            cmaxf = __uint_as_float((unsigned)(rk >> 32));
            ckey = rk;
        }
    }
    // wave partial for step 1
    {
        unsigned long long wp = ckey;
        #pragma unroll
        for (int off = 32; off; off >>= 1) {
            unsigned long long o = __shfl_xor(wp, off);
            if (o > wp) wp = o;
        }
        wavemax = wp;
        if (lane == 0) rv64[1][w] = wp;
    }
    if (tid == 0) {
        ids[0] = 0;
        out_subpos[0] = s0x; out_subpos[1] = s0y; out_subpos[2] = s0z;
        out_subbatch[0] = (float)batch[0];
    }
    __syncthreads();

    // ---- main loop ----
    for (int t = 1; t < M_CL; ++t) {
        const int tb = t & 1;
        // A: redundant final reduce over 8 wave partials
        unsigned long long bk = rv64[tb][0];
        #pragma unroll
        for (int u = 1; u < 8; ++u) {
            unsigned long long o = rv64[tb][u];
            if (o > bk) bk = o;
        }
        const int i2 = (int)(0x7fffffffu - (unsigned)(bk & 0xffffffffu));
        const float sx = posx[i2], sy = posy[i2], sz = posz[i2];
        if (tid == 0) {
            ids[t] = i2;
            out_subpos[3 * t + 0] = sx;
            out_subpos[3 * t + 1] = sy;
            out_subpos[3 * t + 2] = sz;
            out_subbatch[t] = (float)batch[i2];
        }
        // prune test: lane k (<32) tests region k
        float ex = sx - cenx, ey = sy - ceny, ez = sz - cenz;
        float dc2 = (ex * ex + ey * ey) + ez * ez;
        float lb = sqrtf(dc2) * 0.9995f - rad;
        bool aff = (lane < 32) && !(lb > 0.0f && lb * lb * 0.999f >= cmaxf);
        unsigned long long m = __ballot(aff);

        // B: update affected regions (wave-uniform skip per section)
        #pragma unroll
        for (int k = 0; k < 32; ++k) {
            if (m & (1ull << k)) {
                unsigned long long rk = 0ull;
                #pragma unroll
                for (int p = 0; p < 2; ++p) {
                    int gi = wb + k * 128 + p * 64 + lane;
                    float dx = cxr[k][p] - sx;
                    float dy = cyr[k][p] - sy;
                    float dz = czr[k][p] - sz;
                    float xx = dx * dx, yy = dy * dy, zz = dz * dz;
                    float d = (xx + yy) + zz;
                    float nm = fminf(mdL[gi], d);
                    mdL[gi] = nm;
                    unsigned long long kp = ((unsigned long long)__float_as_uint(nm) << 32)
                                          | (unsigned long long)(0x7fffffffu - oidr[k][p]);
                    if (kp > rk) rk = kp;
                }
                #pragma unroll
                for (int off = 32; off; off >>= 1) {
                    unsigned long long o = __shfl_xor(rk, off);
                    if (o > rk) rk = o;
                }
                if (lane == k) {
                    ckey = rk;
                    cmaxf = __uint_as_float((unsigned)(rk >> 32));
                }
            }
        }

        // C: wave partial (recompute only if this wave changed)
        if (m) {
            unsigned long long wp = ckey;
            #pragma unroll
            for (int off = 32; off; off >>= 1) {
                unsigned long long o = __shfl_xor(wp, off);
                if (o > wp) wp = o;
            }
            wavemax = wp;
        }
        if (lane == 0) rv64[(t + 1) & 1][w] = wavemax;
        __syncthreads();
    }
}

// ---------------------------------------------------------------------------
// 2) GEMM h = x@W + b (f32 vector ALU) + fused per-block column sum / sumsq.
__global__ __launch_bounds__(256) void gemm_stats_kernel(
    const float* __restrict__ x, const float* __restrict__ W, const float* __restrict__ bias,
    float* __restrict__ h, float* __restrict__ psum, float* __restrict__ psumsq) {
    __shared__ __align__(16) float Wl[64 * 128];
    __shared__ float xl[64 * 64];
    __shared__ float st[8 * 128 * 2];

    const int t = threadIdx.x;
    const int r0 = blockIdx.x * 64;
    #pragma unroll
    for (int u = 0; u < 32; ++u) Wl[u * 256 + t] = W[u * 256 + t];
    #pragma unroll
    for (int u = 0; u < 16; ++u) { int f = u * 256 + t; xl[f] = x[r0 * 64 + f]; }
    __syncthreads();

    const int cg = t & 31;
    const int rg = t >> 5;
    float acc[8][4];
    #pragma unroll
    for (int j = 0; j < 8; ++j)
        #pragma unroll
        for (int cc = 0; cc < 4; ++cc) acc[j][cc] = 0.0f;

    #pragma unroll 4
    for (int k = 0; k < 64; ++k) {
        float4 w4 = *reinterpret_cast<const float4*>(&Wl[k * 128 + cg * 4]);
        #pragma unroll
        for (int j = 0; j < 8; ++j) {
            float xv = xl[(rg * 8 + j) * 64 + k];
            acc[j][0] = fmaf(xv, w4.x, acc[j][0]);
            acc[j][1] = fmaf(xv, w4.y, acc[j][1]);
            acc[j][2] = fmaf(xv, w4.z, acc[j][2]);
            acc[j][3] = fmaf(xv, w4.w, acc[j][3]);
        }
    }
    float4 b4 = *reinterpret_cast<const float4*>(&bias[cg * 4]);
    float s1[4] = {0, 0, 0, 0}, s2[4] = {0, 0, 0, 0};
    #pragma unroll
    for (int j = 0; j < 8; ++j) {
        float4 hv;
        hv.x = acc[j][0] + b4.x;
        hv.y = acc[j][1] + b4.y;
        hv.z = acc[j][2] + b4.z;
        hv.w = acc[j][3] + b4.w;
        *reinterpret_cast<float4*>(&h[(r0 + rg * 8 + j) * 128 + cg * 4]) = hv;
        s1[0] += hv.x; s2[0] += hv.x * hv.x;
        s1[1] += hv.y; s2[1] += hv.y * hv.y;
        s1[2] += hv.z; s2[2] += hv.z * hv.z;
        s1[3] += hv.w; s2[3] += hv.w * hv.w;
    }
    #pragma unroll
    for (int cc = 0; cc < 4; ++cc) {
        st[(rg * 128 + cg * 4 + cc) * 2 + 0] = s1[cc];
        st[(rg * 128 + cg * 4 + cc) * 2 + 1] = s2[cc];
    }
    __syncthreads();
    if (t < 128) {
        float a = 0.0f, q = 0.0f;
        #pragma unroll
        for (int g = 0; g < 8; ++g) {
            a += st[(g * 128 + t) * 2 + 0];
            q += st[(g * 128 + t) * 2 + 1];
        }
        psum[blockIdx.x * 128 + t] = a;
        psumsq[blockIdx.x * 128 + t] = q;
    }
}

// ---------------------------------------------------------------------------
__global__ void bn_finalize_kernel(const float* __restrict__ psum, const float* __restrict__ psumsq,
                                   const float* __restrict__ gamma, const float* __restrict__ beta,
                                   float* __restrict__ scale, float* __restrict__ shift) {
    int c = threadIdx.x;
    float s = 0.0f, q = 0.0f;
    #pragma unroll 8
    for (int p = 0; p < 512; ++p) {
        s += psum[p * 128 + c];
        q += psumsq[p * 128 + c];
    }
    float mean = s * (1.0f / N_PTS);
    float var = q * (1.0f / N_PTS) - mean * mean;
    float sc = gamma[c] * rsqrtf(var + BN_EPS_C);
    scale[c] = sc;
    shift[c] = beta[c] - mean * sc;
}

// ---------------------------------------------------------------------------
// 4) kNN: one wave per query; per-lane top-16 lex (d, idx); shuffle merge.
__global__ __launch_bounds__(256) void knn_kernel(
    const float* __restrict__ posx, const float* __restrict__ posy, const float* __restrict__ posz,
    const int* __restrict__ ids, int* __restrict__ nn) {
    const int lane = threadIdx.x & 63;
    const int q = blockIdx.x * 4 + (threadIdx.x >> 6);
    const int qi = ids[q];
    const float qx = posx[qi], qy = posy[qi], qz = posz[qi];

    float dv[16]; int di[16];
    #pragma unroll
    for (int j = 0; j < 16; ++j) { dv[j] = FLT_MAX; di[j] = 0x7fffffff; }
    float wm = FLT_MAX; int wmi = 0x7fffffff; int wslot = 0;

    for (int s = 0; s < N_PTS / 64; ++s) {
        int i = s * 64 + lane;
        float dx = posx[i] - qx, dy = posy[i] - qy, dz = posz[i] - qz;
        float d = fmaf(dx, dx, fmaf(dy, dy, dz * dz));
        if (d < wm || (d == wm && i < wmi)) {
            #pragma unroll
            for (int j = 0; j < 16; ++j)
                if (j == wslot) { dv[j] = d; di[j] = i; }
            wm = -1.0f; wmi = -1;
            #pragma unroll
            for (int j = 0; j < 16; ++j) {
                bool g = (dv[j] > wm) || (dv[j] == wm && di[j] > wmi);
                if (g) { wm = dv[j]; wmi = di[j]; wslot = j; }
            }
        }
    }
    for (int rr = 0; rr < 16; ++rr) {
        float bv = FLT_MAX; int bidx = 0x7fffffff;
        #pragma unroll
        for (int j = 0; j < 16; ++j) {
            bool g = (dv[j] < bv) || (dv[j] == bv && di[j] < bidx);
            if (g) { bv = dv[j]; bidx = di[j]; }
        }
        #pragma unroll
        for (int off = 32; off; off >>= 1) {
            float ov = __shfl_xor(bv, off);
            int oi = __shfl_xor(bidx, off);
            if (ov < bv || (ov == bv && oi < bidx)) { bv = ov; bidx = oi; }
        }
        if (lane == 0) nn[q * 16 + rr] = bidx;
        #pragma unroll
        for (int j = 0; j < 16; ++j)
            if (di[j] == bidx) { dv[j] = FLT_MAX; di[j] = 0x7fffffff; }
    }
}

// ---------------------------------------------------------------------------
__global__ __launch_bounds__(256) void pool_kernel(
    const float* __restrict__ h, const int* __restrict__ nn,
    const float* __restrict__ scale, const float* __restrict__ shift,
    float* __restrict__ out) {
    const int t = threadIdx.x;
    const int c = t & 127;
    const int m = blockIdx.x * 2 + (t >> 7);
    const float sc = scale[c], sh = shift[c];
    float mx = -FLT_MAX;
    #pragma unroll
    for (int k = 0; k < 16; ++k) {
        int n = nn[m * 16 + k];
        float hv = h[n * 128 + c];
        mx = fmaxf(mx, fmaf(hv, sc, sh));
    }
    out[m * 128 + c] = fmaxf(mx, 0.0f);
}

// ---------------------------------------------------------------------------
extern "C" void kernel_launch(void* const* d_in, const int* in_sizes, int n_in,
                              void* d_out, int out_size, void* d_ws, size_t ws_size,
                              hipStream_t stream) {
    const float* x     = (const float*)d_in[0];
    const float* pos   = (const float*)d_in[1];
    const int*   batch = (const int*)d_in[2];
    const float* W     = (const float*)d_in[3];
    const float* b     = (const float*)d_in[4];
    const float* gamma = (const float*)d_in[5];
    const float* beta  = (const float*)d_in[6];
    (void)in_sizes; (void)n_in; (void)out_size; (void)ws_size;

    float* out       = (float*)d_out;
    float* sub_pos   = out + (size_t)M_CL * OUT_C;
    float* sub_batch = sub_pos + (size_t)M_CL * 3;

    char* w8 = (char*)d_ws;
    float* posx   = (float*)(w8 + 0);
    float* posy   = (float*)(w8 + 131072);
    float* posz   = (float*)(w8 + 262144);
    float* psx    = (float*)(w8 + 393216);
    float* psy    = (float*)(w8 + 524288);
    float* psz    = (float*)(w8 + 655360);
    int*   soidx  = (int*)  (w8 + 786432);
    int*   cellid = (int*)  (w8 + 917504);
    int*   hist   = (int*)  (w8 + 1048576);
    int*   startb = (int*)  (w8 + 1064960);
    int*   cur    = (int*)  (w8 + 1081344);
    int*   ids    = (int*)  (w8 + 1097728);
    int*   nn     = (int*)  (w8 + 1130496);
    // dead-region reuse (stream-ordered):
    float* psum   = (float*)(w8 + 393216);   // over psx/psy (dead after fps)
    float* psumsq = (float*)(w8 + 655360);   // over psz/soidx (dead after fps)
    float* scale  = (float*)(w8 + 1048576);  // over hist (dead after scatter)
    float* shift  = (float*)(w8 + 1049088);
    float* h      = (float*)(w8 + 2097152);

    zero_kernel<<<32, 256, 0, stream>>>(hist, cur);
    prep_kernel<<<128, 256, 0, stream>>>(pos, posx, posy, posz, cellid, hist);
    scan_kernel<<<1, 1024, 0, stream>>>(hist, startb);
    scatter_kernel<<<128, 256, 0, stream>>>(posx, posy, posz, cellid, startb, cur,
                                            psx, psy, psz, soidx);
    fps_kernel<<<1, 512, 0, stream>>>(psx, psy, psz, soidx,
                                      posx, posy, posz, batch,
                                      ids, sub_pos, sub_batch);
    gemm_stats_kernel<<<512, 256, 0, stream>>>(x, W, b, h, psum, psumsq);
    bn_finalize_kernel<<<1, 128, 0, stream>>>(psum, psumsq, gamma, beta, scale, shift);
    knn_kernel<<<2048, 256, 0, stream>>>(posx, posy, posz, ids, nn);
    pool_kernel<<<4096, 256, 0, stream>>>(h, nn, scale, shift, out);
}